// Round 1
// baseline (412.980 us; speedup 1.0000x reference)
//
#include <hip/hip_runtime.h>
#include <math.h>

// RAMAC: x (16,1024,64,64) f32 -> out (16,1024) f32
// v[b,c] = sum over 15 macs (full image counted twice):
//   mac_r = vt_r[b,c] / (||vt_r[b,:]||2 + eps) * wgt_r
//   vt_r[b,c] = max over region r of x[b,c,:,:]
//   wgt_r = count(tt in region over ALL b) / area_r, zeroed if <= 1/3
//   tt[b,h,w] = (sum_c x[b,c,h,w]) - mean > 0, mean global over (b,h,w)
//
// 14 distinct regions (H=W=64, L=3):
//   r0 : rows[0,64) x cols[0,64)            (weight x2, area 4096)
//   r1-4 : {[0,42),[22,64)}^2               (area 1764)
//   r5-13: {[0,32),[16,48),[32,64)}^2       (area 1024)

#define NB 16
#define NC 1024
#define G 16              // channels per block in k1 (was 32; 1024 blocks = 4/CU)
#define NCHUNK (NC / G)   // 64

// ---------------- DPP helpers ------------------------------------------
template <int ctrl, int rm, int bm>
__device__ __forceinline__ float maxdpp(float x) {
  int xi = __float_as_int(x);
  int yi = __builtin_amdgcn_update_dpp(xi, xi, ctrl, rm, bm, false);
  return fmaxf(x, __int_as_float(yi));
}
// full-wave masked reduce, result valid in lane 63
__device__ __forceinline__ float wave_max64(float x) {
  x = maxdpp<0x111, 0xf, 0xf>(x);  // row_shr:1
  x = maxdpp<0x112, 0xf, 0xf>(x);  // row_shr:2
  x = maxdpp<0x114, 0xf, 0xe>(x);  // row_shr:4
  x = maxdpp<0x118, 0xf, 0xc>(x);  // row_shr:8
  x = maxdpp<0x142, 0xa, 0xf>(x);  // row_bcast:15
  x = maxdpp<0x143, 0x8, 0xf>(x);  // row_bcast:31
  return x;                        // lane 63 holds wave max
}
__device__ __forceinline__ float shflxor_max(float x, int m) {
  return fmaxf(x, __shfl_xor(x, m));
}

// ---------------- Kernel 1: single pass over x --------------------------
// grid (NCHUNK, NB), block 256. Thread t owns float4 indices {t+256k, k=0..3}:
//   fb = t&15 (cols 4fb..4fb+3), row_k = (t>>4)+16k.
// Software-pipelined over channels; region maxes staged per-channel in LDS,
// written once per block as coalesced float4.
__global__ __launch_bounds__(256, 4) void k1_main(
    const float4* __restrict__ x, float4* __restrict__ vtp4,
    float4* __restrict__ spart4, float* __restrict__ total,
    int* __restrict__ cnt) {
  const int t = threadIdx.x;
  const int chunk = blockIdx.x;
  const int b = blockIdx.y;
  if (chunk == 0 && b == 0) {  // zero accumulators consumed by k2/k3
    if (t == 0) *total = 0.f;
    if (t < 14) cnt[t] = 0;
  }
  const int fb = t & 15;
  const int r0t = t >> 4;
  const int w = t >> 6;
  const int L = t & 63;
  const float NEG = -INFINITY;
  // thread-constant column-interval masks (boundary regions r1-r4 only)
  const bool cAf = (fb <= 9), cAp = (fb == 10);   // [0,42): full / cols 40,41
  const bool cBf = (fb >= 6), cBp = (fb == 5);    // [22,64): full / cols 22,23
  // row-interval edge conditions
  const bool rAk2 = (r0t < 10);  // k=2 rows 32..47 in [0,42)
  const bool rBk1 = (r0t >= 6);  // k=1 rows 16..31 in [22,64)

  __shared__ float4 sm4[14][G];  // [r][ci] holds w=0..3 partials

  float4 sa0 = {0, 0, 0, 0}, sa1 = {0, 0, 0, 0}, sa2 = {0, 0, 0, 0},
         sa3 = {0, 0, 0, 0};
  const float4* img = x + (((size_t)(b * NC + chunk * G)) << 10);

  // Shared butterfly chain for 16-aligned column intervals.
  // Input V = per-lane row-interval fold (valid for ALL lanes, cols 4fb..4fb+3).
  // Steps (all involutions, lane-mapping direction-proof):
  //   xor16, xor32  -> collapse the 4 r0t-groups within the wave (keep fb)
  //   quad xor1/2   -> 4-lane-group max = 16-col-block max G[fb>>2]
  //   half_mirror   -> lanes fb 0-7: max(G0,G1)=cols[0,32); fb 8-15: cols[32,64)
  //   shfl_xor 12   -> lanes fb 4-11: max(G1,G2)=cols[16,48)
  auto chain = [&](float V, float& outCE, float& outD) {
    float a = shflxor_max(V, 16);
    a = shflxor_max(a, 32);
    float b4 = maxdpp<0xB1, 0xf, 0xf>(a);   // quad_perm [1,0,3,2] = xor1
    b4 = maxdpp<0x4E, 0xf, 0xf>(b4);        // quad_perm [2,3,0,1] = xor2
    outD = fmaxf(b4, __shfl_xor(b4, 12));   // lanes 4-11 valid: col [16,48)
    outCE = maxdpp<0x141, 0xf, 0xf>(b4);    // row_half_mirror: C @0-7, E @8-15
  };

  auto process = [&](float4 v0, float4 v1, float4 v2, float4 v3, int ci) {
    sa0.x += v0.x; sa0.y += v0.y; sa0.z += v0.z; sa0.w += v0.w;
    sa1.x += v1.x; sa1.y += v1.y; sa1.z += v1.z; sa1.w += v1.w;
    sa2.x += v2.x; sa2.y += v2.y; sa2.z += v2.z; sa2.w += v2.w;
    sa3.x += v3.x; sa3.y += v3.y; sa3.z += v3.z; sa3.w += v3.w;

    // per-row-group float4 maxes
    float m0 = fmaxf(fmaxf(v0.x, v0.y), fmaxf(v0.z, v0.w));
    float m1 = fmaxf(fmaxf(v1.x, v1.y), fmaxf(v1.z, v1.w));
    float m2 = fmaxf(fmaxf(v2.x, v2.y), fmaxf(v2.z, v2.w));
    float m3 = fmaxf(fmaxf(v3.x, v3.y), fmaxf(v3.z, v3.w));
    // boundary partials: pA = cols 40,41 (fb==10: .x,.y); pB = cols 22,23 (.z,.w)
    float pA0 = fmaxf(v0.x, v0.y), pA1 = fmaxf(v1.x, v1.y);
    float pA2 = fmaxf(v2.x, v2.y), pA3 = fmaxf(v3.x, v3.y);
    float pB0 = fmaxf(v0.z, v0.w), pB1 = fmaxf(v1.z, v1.w);
    float pB2 = fmaxf(v2.z, v2.w), pB3 = fmaxf(v3.z, v3.w);

    // row folds: m01 = rows[0,32), m12 = rows[16,48), m23 = rows[32,64)
    float m01 = fmaxf(m0, m1), m12 = fmaxf(m1, m2), m23 = fmaxf(m2, m3);
    float MAm = fmaxf(m01, rAk2 ? m2 : NEG);   // rows [0,42)
    float MBm = fmaxf(m23, rBk1 ? m1 : NEG);   // rows [22,64)
    float MApA = fmaxf(fmaxf(pA0, pA1), rAk2 ? pA2 : NEG);
    float MApB = fmaxf(fmaxf(pB0, pB1), rAk2 ? pB2 : NEG);
    float MBpA = fmaxf(fmaxf(pA2, pA3), rBk1 ? pA1 : NEG);
    float MBpB = fmaxf(fmaxf(pB2, pB3), rBk1 ? pB1 : NEG);

    // r0-r4: unaligned boundaries -> masked full-wave reduction (as before)
    float g0 = fmaxf(m01, m23);
    float g1 = cAf ? MAm : (cAp ? MApA : NEG);
    float g2 = cBf ? MAm : (cBp ? MApB : NEG);
    float g3 = cAf ? MBm : (cAp ? MBpA : NEG);
    float g4 = cBf ? MBm : (cBp ? MBpB : NEG);
    g0 = wave_max64(g0); g1 = wave_max64(g1); g2 = wave_max64(g2);
    g3 = wave_max64(g3); g4 = wave_max64(g4);

    // r5-r13: three shared chains give all 9 aligned regions
    float ceC, dC, ceD, dD, ceE, dE;
    chain(m01, ceC, dC);  // row [0,32)  -> r5(cC@L0) r6(cD@L4) r7(cE@L8)
    chain(m12, ceD, dD);  // row [16,48) -> r8 r9 r10
    chain(m23, ceE, dE);  // row [32,64) -> r11 r12 r13

    float* smf = (float*)&sm4[0][0];
    const int o = (ci << 2) + w;     // [r][ci][w], r stride = G*4
    const int RS = G * 4;
    if (L == 63) {                   // per-wave partials for r0-r4
      smf[o]          = g0;  smf[o + 1 * RS] = g1;
      smf[o + 2 * RS] = g2;  smf[o + 3 * RS] = g3;
      smf[o + 4 * RS] = g4;
    }
    if (L == 0) {                    // col [0,32)
      smf[o + 5 * RS] = ceC; smf[o + 8 * RS] = ceD; smf[o + 11 * RS] = ceE;
    }
    if (L == 4) {                    // col [16,48)
      smf[o + 6 * RS] = dC;  smf[o + 9 * RS] = dD;  smf[o + 12 * RS] = dE;
    }
    if (L == 8) {                    // col [32,64)
      smf[o + 7 * RS] = ceC; smf[o + 10 * RS] = ceD; smf[o + 13 * RS] = ceE;
    }
  };

  // software pipeline: prefetch ci+1 before processing ci
  float4 v0 = img[t], v1 = img[t + 256], v2 = img[t + 512], v3 = img[t + 768];
  for (int ci = 0; ci < G - 1; ++ci) {
    const float4* q = img + (((size_t)(ci + 1)) << 10);
    float4 n0 = q[t], n1 = q[t + 256], n2 = q[t + 512], n3 = q[t + 768];
    process(v0, v1, v2, v3, ci);
    v0 = n0; v1 = n1; v2 = n2; v3 = n3;
  }
  process(v0, v1, v2, v3, G - 1);

  // channel-sum chunk partials (partial over this block's G channels)
  const int sb = ((chunk * NB + b) << 10);
  spart4[sb + t] = sa0;
  spart4[sb + t + 256] = sa1;
  spart4[sb + t + 512] = sa2;
  spart4[sb + t + 768] = sa3;

  __syncthreads();
  for (int i = t; i < 14 * G; i += 256) {  // coalesced float4 per (r, ci)
    const int r = i >> 4, ci = i & 15;     // G == 16
    vtp4[r * (NB * NC) + (b << 10) + chunk * G + ci] = sm4[r][ci];
  }
}

// ---------------- Kernel 2 (merged): s+total | vt+nrm -------------------
// blocks 0..63: s = sum over chunks, total += sum(s)
// blocks 64..287: rb = blk-64: vt = max of 4 wave partials, nrm[rb]
__global__ __launch_bounds__(256) void k2_mid(
    const float4* __restrict__ spart4, float4* __restrict__ s4,
    float* __restrict__ total, const float4* __restrict__ vtp4,
    float* __restrict__ vt, float* __restrict__ nrm) {
  const int blk = blockIdx.x;
  const int t = threadIdx.x;
  __shared__ float red[4];
  if (blk < 64) {
    const int id = blk * 256 + t;  // 0..16383 (b*1024 + f4)
    float4 acc = {0, 0, 0, 0};
    for (int ch = 0; ch < NCHUNK; ++ch) {
      float4 v = spart4[(ch << 14) + id];
      acc.x += v.x; acc.y += v.y; acc.z += v.z; acc.w += v.w;
    }
    s4[id] = acc;
    float ts = (acc.x + acc.y) + (acc.z + acc.w);
    for (int off = 1; off < 64; off <<= 1) ts += __shfl_xor(ts, off);
    if ((t & 63) == 0) atomicAdd(total, ts);
  } else {
    const int rb = blk - 64;  // r*16 + b, 0..223
    float acc = 0.f;
#pragma unroll
    for (int k = 0; k < 4; ++k) {
      const int c = t + 256 * k;
      float4 v = vtp4[(rb << 10) + c];
      float m = fmaxf(fmaxf(v.x, v.y), fmaxf(v.z, v.w));
      vt[(rb << 10) + c] = m;
      acc += m * m;
    }
    for (int off = 1; off < 64; off <<= 1) acc += __shfl_xor(acc, off);
    if ((t & 63) == 0) red[t >> 6] = acc;
    __syncthreads();
    if (t == 0) nrm[rb] = sqrtf(red[0] + red[1] + red[2] + red[3]);
  }
}

// ---------------- Kernel 3: region counts of tt -------------------------
// 64 blocks: block = b*4 + quarter; each covers 1024 pixels of image b.
__global__ __launch_bounds__(256) void k3_cnt(const float* __restrict__ s,
                                              const float* __restrict__ total,
                                              int* __restrict__ cnt) {
  const int b = blockIdx.x >> 2;
  const int q = blockIdx.x & 3;
  const int t = threadIdx.x;
  const float mean = *total * (1.0f / 65536.0f);
  int loc[14];
#pragma unroll
  for (int r = 0; r < 14; ++r) loc[r] = 0;
#pragma unroll
  for (int k = 0; k < 4; ++k) {
    const int p = t + 256 * (q * 4 + k);
    const int row = p >> 6, col = p & 63;
    const bool tt = s[(b << 12) + p] > mean;
    if (tt) {
      const bool rA = row < 42, rB = row >= 22, rC = row < 32;
      const bool rD = (row >= 16) && (row < 48), rE = row >= 32;
      const bool cA = col < 42, cB = col >= 22, cC = col < 32;
      const bool cD = (col >= 16) && (col < 48), cE = col >= 32;
      loc[0]++;
      loc[1] += rA && cA;  loc[2] += rA && cB;
      loc[3] += rB && cA;  loc[4] += rB && cB;
      loc[5] += rC && cC;  loc[6] += rC && cD;  loc[7] += rC && cE;
      loc[8] += rD && cC;  loc[9] += rD && cD;  loc[10] += rD && cE;
      loc[11] += rE && cC; loc[12] += rE && cD; loc[13] += rE && cE;
    }
  }
#pragma unroll
  for (int r = 0; r < 14; ++r) {
    int v = loc[r];
    for (int off = 1; off < 64; off <<= 1) v += __shfl_xor(v, off);
    if ((t & 63) == 0) atomicAdd(&cnt[r], v);
  }
}

// ---------------- Kernel 4: epilogue ------------------------------------
__global__ __launch_bounds__(256) void k4_out(const float* __restrict__ vt,
                                              const float* __restrict__ nrm,
                                              const int* __restrict__ cnt,
                                              float* __restrict__ out) {
  const int id = blockIdx.x * 256 + threadIdx.x;  // b*1024 + c
  const int b = id >> 10;
  float acc = 0.f;
#pragma unroll
  for (int r = 0; r < 14; ++r) {
    const float area = (r == 0) ? 4096.f : ((r <= 4) ? 1764.f : 1024.f);
    float wgt = (float)cnt[r] / area;
    if (wgt <= (1.0f / 3.0f)) wgt = 0.f;
    const float mult = (r == 0) ? 2.f : 1.f;
    acc += mult * wgt * vt[r * 16384 + id] / (nrm[r * 16 + b] + 1e-6f);
  }
  out[id] = acc;
}

extern "C" void kernel_launch(void* const* d_in, const int* in_sizes, int n_in,
                              void* d_out, int out_size, void* d_ws,
                              size_t ws_size, hipStream_t stream) {
  const float* x = (const float*)d_in[0];
  float* out = (float*)d_out;

  // workspace layout (floats)
  float* ws = (float*)d_ws;
  float* vtp = ws;                       // 14*16*1024*4   = 917504
  float* spart = vtp + 917504;           // 64*16*4096     = 4194304
  float* s = spart + 4194304;            // 65536
  float* vt = s + 65536;                 // 14*16*1024     = 229376
  float* nrm = vt + 229376;              // 224
  float* total = nrm + 224;              // 1
  int* cnt = (int*)(total + 1);          // 14
  // total ~21.7 MB

  k1_main<<<dim3(NCHUNK, NB), 256, 0, stream>>>(
      (const float4*)x, (float4*)vtp, (float4*)spart, total, cnt);
  k2_mid<<<64 + 224, 256, 0, stream>>>((const float4*)spart, (float4*)s, total,
                                       (const float4*)vtp, vt, nrm);
  k3_cnt<<<64, 256, 0, stream>>>(s, total, cnt);
  k4_out<<<64, 256, 0, stream>>>(vt, nrm, cnt, out);
}

// Round 2
// 411.360 us; speedup vs baseline: 1.0039x; 1.0039x over previous
//
#include <hip/hip_runtime.h>
#include <math.h>

// RAMAC: x (16,1024,64,64) f32 -> out (16,1024) f32
// v[b,c] = sum over 15 macs (full image counted twice):
//   mac_r = vt_r[b,c] / (||vt_r[b,:]||2 + eps) * wgt_r
//   vt_r[b,c] = max over region r of x[b,c,:,:]
//   wgt_r = count(tt in region over ALL b) / area_r, zeroed if <= 1/3
//   tt[b,h,w] = (sum_c x[b,c,h,w]) - mean > 0, mean global over (b,h,w)
//
// 14 distinct regions (H=W=64, L=3):
//   r0 : rows[0,64) x cols[0,64)            (weight x2, area 4096)
//   r1-4 : {[0,42),[22,64)}^2               (area 1764)
//   r5-13: {[0,32),[16,48),[32,64)}^2       (area 1024)

#define NB 16
#define NC 1024
#define G 32              // channels per block in k1 (round-0 geometry)
#define NCHUNK (NC / G)   // 32

// ---------------- DPP helpers ------------------------------------------
template <int ctrl, int rm, int bm>
__device__ __forceinline__ float maxdpp(float x) {
  int xi = __float_as_int(x);
  int yi = __builtin_amdgcn_update_dpp(xi, xi, ctrl, rm, bm, false);
  return fmaxf(x, __int_as_float(yi));
}
// full-wave masked reduce, result valid in lane 63
__device__ __forceinline__ float wave_max64(float x) {
  x = maxdpp<0x111, 0xf, 0xf>(x);  // row_shr:1
  x = maxdpp<0x112, 0xf, 0xf>(x);  // row_shr:2
  x = maxdpp<0x114, 0xf, 0xe>(x);  // row_shr:4
  x = maxdpp<0x118, 0xf, 0xc>(x);  // row_shr:8
  x = maxdpp<0x142, 0xa, 0xf>(x);  // row_bcast:15
  x = maxdpp<0x143, 0x8, 0xf>(x);  // row_bcast:31
  return x;                        // lane 63 holds wave max
}
__device__ __forceinline__ float swz16_max(float x) {  // xor16, 1 DS op
  int y = __builtin_amdgcn_ds_swizzle(__float_as_int(x), 0x401F);
  return fmaxf(x, __int_as_float(y));
}
__device__ __forceinline__ float shflxor_max(float x, int m) {
  return fmaxf(x, __shfl_xor(x, m));
}

// ---------------- Kernel 1: single pass over x --------------------------
// grid (NCHUNK, NB), block 256. Thread t owns float4 indices {t+256k, k=0..3}:
//   fb = t&15 (cols 4fb..4fb+3), row_k = (t>>4)+16k.
// Software-pipelined over channels; region maxes staged per-channel in LDS,
// written once per block as coalesced float4.
__global__ __launch_bounds__(256) void k1_main(
    const float4* __restrict__ x, float4* __restrict__ vtp4,
    float4* __restrict__ spart4, float* __restrict__ total,
    int* __restrict__ cnt) {
  const int t = threadIdx.x;
  const int chunk = blockIdx.x;
  const int b = blockIdx.y;
  if (chunk == 0 && b == 0) {  // zero accumulators consumed by k2/k3
    if (t == 0) *total = 0.f;
    if (t < 14) cnt[t] = 0;
  }
  const int fb = t & 15;
  const int r0t = t >> 4;
  const int w = t >> 6;
  const int L = t & 63;
  const float NEG = -INFINITY;
  // thread-constant column-interval masks (boundary regions r1-r4 only)
  const bool cAf = (fb <= 9), cAp = (fb == 10);   // [0,42): full / cols 40,41
  const bool cBf = (fb >= 6), cBp = (fb == 5);    // [22,64): full / cols 22,23
  // row-interval edge conditions
  const bool rAk2 = (r0t < 10);  // k=2 rows 32..47 in [0,42)
  const bool rBk1 = (r0t >= 6);  // k=1 rows 16..31 in [22,64)

  __shared__ float4 sm4[14][G];  // [r][ci] holds w=0..3 partials

  float4 sa0 = {0, 0, 0, 0}, sa1 = {0, 0, 0, 0}, sa2 = {0, 0, 0, 0},
         sa3 = {0, 0, 0, 0};
  const float4* img = x + (((size_t)(b * NC + chunk * G)) << 10);

  // Butterfly chain for 16-aligned column intervals (mostly DPP).
  // Input V = per-lane row-interval fold (all lanes, cols 4fb..4fb+3).
  // Collapse lane bits {0,1} (quad_perm), {4,5} (swizzle-xor16 + shfl-xor32);
  // result depends only on bits 2-3 = 16-col-group G0..G3.
  //   row_mirror  (g0<->g3, g1<->g2): D = max(G1,G2) valid at fb 4..11
  //   half_mirror (xor bit2)        : C = max(G0,G1) @fb0-7, E = max(G2,G3) @fb8-15
  auto chain = [&](float V, float& outCE, float& outD) {
    float b4 = maxdpp<0xB1, 0xf, 0xf>(V);   // quad_perm [1,0,3,2] = xor1
    b4 = maxdpp<0x4E, 0xf, 0xf>(b4);        // quad_perm [2,3,0,1] = xor2
    b4 = swz16_max(b4);                     // xor16 (DS, imm pattern)
    b4 = shflxor_max(b4, 32);               // xor32 (cross 32-lane half)
    outD = maxdpp<0x140, 0xf, 0xf>(b4);     // row_mirror
    outCE = maxdpp<0x141, 0xf, 0xf>(b4);    // half_mirror
  };

  auto process = [&](float4 v0, float4 v1, float4 v2, float4 v3, int ci) {
    sa0.x += v0.x; sa0.y += v0.y; sa0.z += v0.z; sa0.w += v0.w;
    sa1.x += v1.x; sa1.y += v1.y; sa1.z += v1.z; sa1.w += v1.w;
    sa2.x += v2.x; sa2.y += v2.y; sa2.z += v2.z; sa2.w += v2.w;
    sa3.x += v3.x; sa3.y += v3.y; sa3.z += v3.z; sa3.w += v3.w;

    // per-row-group float4 maxes
    float m0 = fmaxf(fmaxf(v0.x, v0.y), fmaxf(v0.z, v0.w));
    float m1 = fmaxf(fmaxf(v1.x, v1.y), fmaxf(v1.z, v1.w));
    float m2 = fmaxf(fmaxf(v2.x, v2.y), fmaxf(v2.z, v2.w));
    float m3 = fmaxf(fmaxf(v3.x, v3.y), fmaxf(v3.z, v3.w));
    // boundary partials: pA = cols 40,41 (fb==10: .x,.y); pB = cols 22,23 (.z,.w)
    float pA0 = fmaxf(v0.x, v0.y), pA1 = fmaxf(v1.x, v1.y);
    float pA2 = fmaxf(v2.x, v2.y), pA3 = fmaxf(v3.x, v3.y);
    float pB0 = fmaxf(v0.z, v0.w), pB1 = fmaxf(v1.z, v1.w);
    float pB2 = fmaxf(v2.z, v2.w), pB3 = fmaxf(v3.z, v3.w);

    // row folds: m01 = rows[0,32), m12 = rows[16,48), m23 = rows[32,64)
    float m01 = fmaxf(m0, m1), m12 = fmaxf(m1, m2), m23 = fmaxf(m2, m3);
    float MAm = fmaxf(m01, rAk2 ? m2 : NEG);   // rows [0,42)
    float MBm = fmaxf(m23, rBk1 ? m1 : NEG);   // rows [22,64)
    float MApA = fmaxf(fmaxf(pA0, pA1), rAk2 ? pA2 : NEG);
    float MApB = fmaxf(fmaxf(pB0, pB1), rAk2 ? pB2 : NEG);
    float MBpA = fmaxf(fmaxf(pA2, pA3), rBk1 ? pA1 : NEG);
    float MBpB = fmaxf(fmaxf(pB2, pB3), rBk1 ? pB1 : NEG);

    // r1-r4: unaligned 42/22 boundaries -> masked full-wave reduction
    float g1 = cAf ? MAm : (cAp ? MApA : NEG);
    float g2 = cBf ? MAm : (cBp ? MApB : NEG);
    float g3 = cAf ? MBm : (cAp ? MBpA : NEG);
    float g4 = cBf ? MBm : (cBp ? MBpB : NEG);
    g1 = wave_max64(g1); g2 = wave_max64(g2);
    g3 = wave_max64(g3); g4 = wave_max64(g4);

    // r5-r13: three chains give all 9 aligned regions
    float ce01, d01, ce12, d12, ce23, d23;
    chain(m01, ce01, d01);  // row [0,32)  -> r5(C@L0) r6(D@L4) r7(E@L8)
    chain(m12, ce12, d12);  // row [16,48) -> r8 r9 r10
    chain(m23, ce23, d23);  // row [32,64) -> r11 r12 r13

    // r0 composed from chains: C/E halves over all rows, then mirror-join
    float rf = fmaxf(ce01, ce23);
    float r0v = maxdpp<0x140, 0xf, 0xf>(rf);  // valid at all lanes

    float* smf = (float*)&sm4[0][0];
    const int o = (ci << 2) + w;     // [r][ci][w], r stride = G*4
    const int RS = G * 4;
    if (L == 63) {                   // per-wave partials for r1-r4
      smf[o + 1 * RS] = g1;  smf[o + 2 * RS] = g2;
      smf[o + 3 * RS] = g3;  smf[o + 4 * RS] = g4;
    }
    if (L == 0) {                    // r0 + col [0,32)
      smf[o]          = r0v;
      smf[o + 5 * RS] = ce01; smf[o + 8 * RS] = ce12; smf[o + 11 * RS] = ce23;
    }
    if (L == 4) {                    // col [16,48)
      smf[o + 6 * RS] = d01;  smf[o + 9 * RS] = d12;  smf[o + 12 * RS] = d23;
    }
    if (L == 8) {                    // col [32,64)
      smf[o + 7 * RS] = ce01; smf[o + 10 * RS] = ce12; smf[o + 13 * RS] = ce23;
    }
  };

  // software pipeline: prefetch ci+1 before processing ci
  float4 v0 = img[t], v1 = img[t + 256], v2 = img[t + 512], v3 = img[t + 768];
  for (int ci = 0; ci < G - 1; ++ci) {
    const float4* q = img + (((size_t)(ci + 1)) << 10);
    float4 n0 = q[t], n1 = q[t + 256], n2 = q[t + 512], n3 = q[t + 768];
    process(v0, v1, v2, v3, ci);
    v0 = n0; v1 = n1; v2 = n2; v3 = n3;
  }
  process(v0, v1, v2, v3, G - 1);

  // channel-sum chunk partials (partial over this block's G channels)
  const int sb = ((chunk * NB + b) << 10);
  spart4[sb + t] = sa0;
  spart4[sb + t + 256] = sa1;
  spart4[sb + t + 512] = sa2;
  spart4[sb + t + 768] = sa3;

  __syncthreads();
  for (int i = t; i < 14 * G; i += 256) {  // coalesced float4 per (r, ci)
    const int r = i / G, ci = i % G;       // G == 32
    vtp4[r * (NB * NC) + (b << 10) + chunk * G + ci] = sm4[r][ci];
  }
}

// ---------------- Kernel 2 (merged): s+total | vt+nrm -------------------
// blocks 0..63: s = sum over chunks, total += sum(s)
// blocks 64..287: rb = blk-64: vt = max of 4 wave partials, nrm[rb]
__global__ __launch_bounds__(256) void k2_mid(
    const float4* __restrict__ spart4, float4* __restrict__ s4,
    float* __restrict__ total, const float4* __restrict__ vtp4,
    float* __restrict__ vt, float* __restrict__ nrm) {
  const int blk = blockIdx.x;
  const int t = threadIdx.x;
  __shared__ float red[4];
  if (blk < 64) {
    const int id = blk * 256 + t;  // 0..16383 (b*1024 + f4)
    float4 acc = {0, 0, 0, 0};
    for (int ch = 0; ch < NCHUNK; ++ch) {
      float4 v = spart4[(ch << 14) + id];
      acc.x += v.x; acc.y += v.y; acc.z += v.z; acc.w += v.w;
    }
    s4[id] = acc;
    float ts = (acc.x + acc.y) + (acc.z + acc.w);
    for (int off = 1; off < 64; off <<= 1) ts += __shfl_xor(ts, off);
    if ((t & 63) == 0) atomicAdd(total, ts);
  } else {
    const int rb = blk - 64;  // r*16 + b, 0..223
    float acc = 0.f;
#pragma unroll
    for (int k = 0; k < 4; ++k) {
      const int c = t + 256 * k;
      float4 v = vtp4[(rb << 10) + c];
      float m = fmaxf(fmaxf(v.x, v.y), fmaxf(v.z, v.w));
      vt[(rb << 10) + c] = m;
      acc += m * m;
    }
    for (int off = 1; off < 64; off <<= 1) acc += __shfl_xor(acc, off);
    if ((t & 63) == 0) red[t >> 6] = acc;
    __syncthreads();
    if (t == 0) nrm[rb] = sqrtf(red[0] + red[1] + red[2] + red[3]);
  }
}

// ---------------- Kernel 3: region counts of tt -------------------------
// 64 blocks: block = b*4 + quarter; each covers 1024 pixels of image b.
__global__ __launch_bounds__(256) void k3_cnt(const float* __restrict__ s,
                                              const float* __restrict__ total,
                                              int* __restrict__ cnt) {
  const int b = blockIdx.x >> 2;
  const int q = blockIdx.x & 3;
  const int t = threadIdx.x;
  const float mean = *total * (1.0f / 65536.0f);
  int loc[14];
#pragma unroll
  for (int r = 0; r < 14; ++r) loc[r] = 0;
#pragma unroll
  for (int k = 0; k < 4; ++k) {
    const int p = t + 256 * (q * 4 + k);
    const int row = p >> 6, col = p & 63;
    const bool tt = s[(b << 12) + p] > mean;
    if (tt) {
      const bool rA = row < 42, rB = row >= 22, rC = row < 32;
      const bool rD = (row >= 16) && (row < 48), rE = row >= 32;
      const bool cA = col < 42, cB = col >= 22, cC = col < 32;
      const bool cD = (col >= 16) && (col < 48), cE = col >= 32;
      loc[0]++;
      loc[1] += rA && cA;  loc[2] += rA && cB;
      loc[3] += rB && cA;  loc[4] += rB && cB;
      loc[5] += rC && cC;  loc[6] += rC && cD;  loc[7] += rC && cE;
      loc[8] += rD && cC;  loc[9] += rD && cD;  loc[10] += rD && cE;
      loc[11] += rE && cC; loc[12] += rE && cD; loc[13] += rE && cE;
    }
  }
#pragma unroll
  for (int r = 0; r < 14; ++r) {
    int v = loc[r];
    for (int off = 1; off < 64; off <<= 1) v += __shfl_xor(v, off);
    if ((t & 63) == 0) atomicAdd(&cnt[r], v);
  }
}

// ---------------- Kernel 4: epilogue ------------------------------------
__global__ __launch_bounds__(256) void k4_out(const float* __restrict__ vt,
                                              const float* __restrict__ nrm,
                                              const int* __restrict__ cnt,
                                              float* __restrict__ out) {
  const int id = blockIdx.x * 256 + threadIdx.x;  // b*1024 + c
  const int b = id >> 10;
  float acc = 0.f;
#pragma unroll
  for (int r = 0; r < 14; ++r) {
    const float area = (r == 0) ? 4096.f : ((r <= 4) ? 1764.f : 1024.f);
    float wgt = (float)cnt[r] / area;
    if (wgt <= (1.0f / 3.0f)) wgt = 0.f;
    const float mult = (r == 0) ? 2.f : 1.f;
    acc += mult * wgt * vt[r * 16384 + id] / (nrm[r * 16 + b] + 1e-6f);
  }
  out[id] = acc;
}

extern "C" void kernel_launch(void* const* d_in, const int* in_sizes, int n_in,
                              void* d_out, int out_size, void* d_ws,
                              size_t ws_size, hipStream_t stream) {
  const float* x = (const float*)d_in[0];
  float* out = (float*)d_out;

  // workspace layout (floats)
  float* ws = (float*)d_ws;
  float* vtp = ws;                       // 14*16*1024*4   = 917504
  float* spart = vtp + 917504;           // 32*16*4096     = 2097152
  float* s = spart + 2097152;            // 65536
  float* vt = s + 65536;                 // 14*16*1024     = 229376
  float* nrm = vt + 229376;              // 224
  float* total = nrm + 224;              // 1
  int* cnt = (int*)(total + 1);          // 14
  // total ~13.3 MB

  k1_main<<<dim3(NCHUNK, NB), 256, 0, stream>>>(
      (const float4*)x, (float4*)vtp, (float4*)spart, total, cnt);
  k2_mid<<<64 + 224, 256, 0, stream>>>((const float4*)spart, (float4*)s, total,
                                       (const float4*)vtp, vt, nrm);
  k3_cnt<<<64, 256, 0, stream>>>(s, total, cnt);
  k4_out<<<64, 256, 0, stream>>>(vt, nrm, cnt, out);
}